// Round 1
// baseline (484.731 us; speedup 1.0000x reference)
//
#include <hip/hip_runtime.h>
#include <stdint.h>

// ---- problem constants ----
#define DIMX 1024
#define DIM_INNER 2048
#define BATCH 4
#define SEQ 4096
#define M_TOTAL (BATCH * SEQ)   // 16384
#define N_HG (2 * DIM_INNER)    // 4096
#define NCHUNK 32               // chunks along S
#define CLEN 128                // steps per chunk (NCHUNK*CLEN == SEQ)

typedef unsigned short u16;
typedef __attribute__((ext_vector_type(8))) short short8;   // 8 x bf16 MFMA frag
typedef __attribute__((ext_vector_type(4))) float floatx4;  // MFMA acc

// ---- bf16 helpers (bit-level, RNE) ----
__device__ __forceinline__ float bflo(uint32_t u) { return __uint_as_float(u << 16); }
__device__ __forceinline__ float bfhi(uint32_t u) { return __uint_as_float(u & 0xffff0000u); }
__device__ __forceinline__ uint32_t f2bf_bits(float f) {
    uint32_t u = __float_as_uint(f);
    return (u + 0x7fffu + ((u >> 16) & 1u)) >> 16;  // round-to-nearest-even
}

// ============================================================
// cast fp32 -> bf16 (vectorized, grid-stride)
// ============================================================
__global__ __launch_bounds__(256) void cast_f32_bf16(const float* __restrict__ in,
                                                     u16* __restrict__ out, int n4) {
    int i = blockIdx.x * blockDim.x + threadIdx.x;
    int stride = gridDim.x * blockDim.x;
    const float4* in4 = (const float4*)in;
    ushort4* out4 = (ushort4*)out;
    for (; i < n4; i += stride) {
        float4 v = in4[i];
        ushort4 o;
        o.x = (u16)f2bf_bits(v.x);
        o.y = (u16)f2bf_bits(v.y);
        o.z = (u16)f2bf_bits(v.z);
        o.w = (u16)f2bf_bits(v.w);
        out4[i] = o;
    }
}

// ============================================================
// transpose + cast: in[R][C] fp32 -> out[C][R] bf16   (64x64 tiles)
// ============================================================
__global__ __launch_bounds__(1024) void transpose_cast(const float* __restrict__ in,
                                                       u16* __restrict__ out, int R, int C) {
    __shared__ float tile[64][65];
    int c0 = blockIdx.x * 64, r0 = blockIdx.y * 64;
    int tx = threadIdx.x, ty = threadIdx.y;
#pragma unroll
    for (int i = ty; i < 64; i += 16)
        tile[i][tx] = in[(size_t)(r0 + i) * C + c0 + tx];
    __syncthreads();
#pragma unroll
    for (int i = ty; i < 64; i += 16)
        out[(size_t)(c0 + i) * R + r0 + tx] = (u16)f2bf_bits(tile[tx][i]);
}

// ============================================================
// bf16 MFMA GEMM: C[M][N] = A[M][K] * B[K][N],  B given transposed as Bt[N][K].
// 128x128 block tile, BK=32, 256 threads (4 waves, each 64x64 = 4x4 MFMA tiles).
// global_load_lds width-16 staging (lane-contiguous LDS placement).
// OUT_BF16: 1 -> store bf16 (u16), 0 -> store fp32.
// ============================================================
template <int OUT_BF16>
__global__ __launch_bounds__(256, 2) void gemm_bf16(const u16* __restrict__ A,
                                                    const u16* __restrict__ Bt,
                                                    void* __restrict__ C,
                                                    const int M, const int N, const int K) {
    __shared__ alignas(16) u16 As[128 * 32];  // [m][k], row stride 32 elems (64B)
    __shared__ alignas(16) u16 Bs[128 * 32];  // [n][k]

    const int tid = threadIdx.x;
    const int lane = tid & 63;
    const int wave = tid >> 6;            // 0..3
    const int wm = (wave >> 1) * 64;      // wave offset in block tile (rows)
    const int wn = (wave & 1) * 64;       // (cols)
    const size_t m0 = (size_t)blockIdx.y * 128;
    const size_t n0 = (size_t)blockIdx.x * 128;

    floatx4 acc[4][4];
#pragma unroll
    for (int i = 0; i < 4; ++i)
#pragma unroll
        for (int j = 0; j < 4; ++j) acc[i][j] = (floatx4){0.f, 0.f, 0.f, 0.f};

    // staging: one wave-issue covers 16 rows x 32 cols bf16 (16 rows x 64B = 1024B)
    const int srow = lane >> 2;        // 0..15 row within issue
    const int scol = (lane & 3) * 8;   // 0/8/16/24 element offset (16B segments)
    const u16* Ag = A + m0 * K + (size_t)(wave * 16 + srow) * K + scol;
    const u16* Bg = Bt + n0 * K + (size_t)(wave * 16 + srow) * K + scol;
    u16* Asw = As + (wave * 16) * 32;  // wave-uniform LDS bases
    u16* Bsw = Bs + (wave * 16) * 32;

    const int fr = lane & 15;          // fragment row/col within 16
    const int fko = (lane >> 4) * 8;   // fragment k offset

    for (int k0 = 0; k0 < K; k0 += 32) {
        __syncthreads();
#pragma unroll
        for (int i = 0; i < 2; ++i) {
            __builtin_amdgcn_global_load_lds(
                (const __attribute__((address_space(1))) uint32_t*)(const void*)(Ag + (size_t)i * 64 * K + k0),
                (__attribute__((address_space(3))) uint32_t*)(void*)(Asw + i * 64 * 32),
                16, 0, 0);
            __builtin_amdgcn_global_load_lds(
                (const __attribute__((address_space(1))) uint32_t*)(const void*)(Bg + (size_t)i * 64 * K + k0),
                (__attribute__((address_space(3))) uint32_t*)(void*)(Bsw + i * 64 * 32),
                16, 0, 0);
        }
        __syncthreads();

        short8 af[4], bfr[4];
#pragma unroll
        for (int i = 0; i < 4; ++i)
            af[i] = *(const short8*)(As + (wm + i * 16 + fr) * 32 + fko);
#pragma unroll
        for (int j = 0; j < 4; ++j)
            bfr[j] = *(const short8*)(Bs + (wn + j * 16 + fr) * 32 + fko);
#pragma unroll
        for (int i = 0; i < 4; ++i)
#pragma unroll
            for (int j = 0; j < 4; ++j)
                acc[i][j] = __builtin_amdgcn_mfma_f32_16x16x32_bf16(af[i], bfr[j], acc[i][j], 0, 0, 0);
    }

    // epilogue: C/D layout col = lane&15, row = (lane>>4)*4 + reg
    const int r0row = (lane >> 4) * 4;
#pragma unroll
    for (int i = 0; i < 4; ++i) {
#pragma unroll
        for (int r = 0; r < 4; ++r) {
            size_t row = m0 + wm + i * 16 + r0row + r;
#pragma unroll
            for (int j = 0; j < 4; ++j) {
                size_t col = n0 + wn + j * 16 + fr;
                float v = acc[i][j][r];
                if (OUT_BF16)
                    ((u16*)C)[row * N + col] = (u16)f2bf_bits(v);
                else
                    ((float*)C)[row * N + col] = v;
            }
        }
    }
}

// ============================================================
// scan helpers: per element  a = sigmoid(-g), v = sigmoid(g)*(relu(h)+0.5)
// recurrence h_t = a_t * h_{t-1} + v_t   (== reference log-space scan)
// hg layout: u16[M][4096], hidden at col c (<2048), gate at 2048+c.
// Each thread handles a PAIR of channels (uint32 loads).
// ============================================================
__device__ __forceinline__ void av_pair(uint32_t hh, uint32_t gg,
                                        float& a0, float& v0, float& a1, float& v1) {
    float h0 = bflo(hh), h1 = bfhi(hh);
    float g0 = bflo(gg), g1 = bfhi(gg);
    g0 = fminf(fmaxf(g0, -30.f), 30.f);
    g1 = fminf(fmaxf(g1, -30.f), 30.f);
    float e0 = __expf(-g0), e1 = __expf(-g1);
    float z0 = 1.f / (1.f + e0), z1 = 1.f / (1.f + e1);
    a0 = e0 * z0;  // sigmoid(-g) = 1 - z
    a1 = e1 * z1;
    v0 = z0 * (fmaxf(h0, 0.f) + 0.5f);
    v1 = z1 * (fmaxf(h1, 0.f) + 0.5f);
}

// Phase A: per-chunk affine summary (A = prod a, V = chunk result from h_in=0)
__global__ __launch_bounds__(256) void scan_chunks(const uint32_t* __restrict__ hg,
                                                   float2* __restrict__ sumAV) {
    const int b = blockIdx.z, ch = blockIdx.y;
    const int cp = blockIdx.x * 256 + threadIdx.x;  // channel-pair 0..1023
    const size_t rowbase = (size_t)b * SEQ + (size_t)ch * CLEN;
    float A0 = 1.f, V0 = 0.f, A1 = 1.f, V1 = 0.f;
    for (int j = 0; j < CLEN; ++j) {
        size_t row = rowbase + j;
        uint32_t hh = hg[row * 2048 + cp];
        uint32_t gg = hg[row * 2048 + 1024 + cp];
        float a0, v0, a1, v1;
        av_pair(hh, gg, a0, v0, a1, v1);
        V0 = fmaf(a0, V0, v0); A0 *= a0;
        V1 = fmaf(a1, V1, v1); A1 *= a1;
    }
    ((float4*)sumAV)[(size_t)(b * NCHUNK + ch) * 1024 + cp] = (float4){A0, V0, A1, V1};
}

// Phase B: sequential carry scan over the 32 chunk summaries per chain
__global__ __launch_bounds__(256) void scan_carry(const float2* __restrict__ sumAV,
                                                  float* __restrict__ carry) {
    const int b = blockIdx.y;
    const int c = blockIdx.x * 256 + threadIdx.x;  // chain channel 0..2047
    float2 s[NCHUNK];
#pragma unroll
    for (int ch = 0; ch < NCHUNK; ++ch)
        s[ch] = sumAV[(size_t)(b * NCHUNK + ch) * 2048 + c];
    float h = 0.f;
#pragma unroll
    for (int ch = 0; ch < NCHUNK; ++ch) {
        carry[(size_t)(b * NCHUNK + ch) * 2048 + c] = h;
        h = fmaf(s[ch].x, h, s[ch].y);
    }
}

// Phase C: replay chunk with carry-in, emit h as bf16
__global__ __launch_bounds__(256) void scan_apply(const uint32_t* __restrict__ hg,
                                                  const float* __restrict__ carry,
                                                  uint32_t* __restrict__ hbuf) {
    const int b = blockIdx.z, ch = blockIdx.y;
    const int cp = blockIdx.x * 256 + threadIdx.x;
    const size_t rowbase = (size_t)b * SEQ + (size_t)ch * CLEN;
    const float2 c2 = ((const float2*)carry)[(size_t)(b * NCHUNK + ch) * 1024 + cp];
    float h0 = c2.x, h1 = c2.y;
    for (int j = 0; j < CLEN; ++j) {
        size_t row = rowbase + j;
        uint32_t hh = hg[row * 2048 + cp];
        uint32_t gg = hg[row * 2048 + 1024 + cp];
        float a0, v0, a1, v1;
        av_pair(hh, gg, a0, v0, a1, v1);
        h0 = fmaf(a0, h0, v0);
        h1 = fmaf(a1, h1, v1);
        hbuf[row * 1024 + cp] = f2bf_bits(h0) | (f2bf_bits(h1) << 16);
    }
}

// ============================================================
extern "C" void kernel_launch(void* const* d_in, const int* in_sizes, int n_in,
                              void* d_out, int out_size, void* d_ws, size_t ws_size,
                              hipStream_t stream) {
    const float* x = (const float*)d_in[0];     // [16384,1024]
    const float* Whg = (const float*)d_in[1];   // [1024,4096]
    const float* Wout = (const float*)d_in[2];  // [2048,1024]

    char* ws = (char*)d_ws;
    size_t off = 0;
    u16* xb = (u16*)(ws + off);        off += (size_t)M_TOTAL * DIMX * 2;        // 32 MB
    u16* whgt = (u16*)(ws + off);      off += (size_t)N_HG * DIMX * 2;           // 8 MB
    u16* woutt = (u16*)(ws + off);     off += (size_t)DIMX * DIM_INNER * 2;      // 4 MB
    u16* hg = (u16*)(ws + off);        off += (size_t)M_TOTAL * N_HG * 2;        // 128 MB
    uint32_t* hbuf = (uint32_t*)(ws + off); off += (size_t)M_TOTAL * DIM_INNER * 2; // 64 MB
    float2* sumAV = (float2*)(ws + off); off += (size_t)BATCH * NCHUNK * DIM_INNER * 8; // 2 MB
    float* carry = (float*)(ws + off);  off += (size_t)BATCH * NCHUNK * DIM_INNER * 4; // 1 MB

    // 1. casts / transposes
    cast_f32_bf16<<<2048, 256, 0, stream>>>(x, xb, M_TOTAL * DIMX / 4);
    transpose_cast<<<dim3(N_HG / 64, DIMX / 64), dim3(64, 16), 0, stream>>>(Whg, whgt, DIMX, N_HG);
    transpose_cast<<<dim3(DIMX / 64, DIM_INNER / 64), dim3(64, 16), 0, stream>>>(Wout, woutt, DIM_INNER, DIMX);

    // 2. GEMM1: hg[16384][4096] = xb @ Whg   (bf16 out)
    gemm_bf16<1><<<dim3(N_HG / 128, M_TOTAL / 128), 256, 0, stream>>>(xb, whgt, hg, M_TOTAL, N_HG, DIMX);

    // 3. chunked scan over S
    scan_chunks<<<dim3(4, NCHUNK, BATCH), 256, 0, stream>>>((const uint32_t*)hg, sumAV);
    scan_carry<<<dim3(8, BATCH), 256, 0, stream>>>(sumAV, carry);
    scan_apply<<<dim3(4, NCHUNK, BATCH), 256, 0, stream>>>((const uint32_t*)hg, carry, hbuf);

    // 4. GEMM2: out[16384][1024] = h @ Wout  (fp32 out)
    gemm_bf16<0><<<dim3(DIMX / 128, M_TOTAL / 128), 256, 0, stream>>>((const u16*)hbuf, woutt, d_out, M_TOTAL, DIMX, DIM_INNER);
}

// Round 3
// 476.505 us; speedup vs baseline: 1.0173x; 1.0173x over previous
//
#include <hip/hip_runtime.h>
#include <stdint.h>

// ---- problem constants ----
#define DIMX 1024
#define DIM_INNER 2048
#define BATCH 4
#define SEQ 4096
#define M_TOTAL (BATCH * SEQ)   // 16384
#define N_HG (2 * DIM_INNER)    // 4096
#define NCHUNK 32               // chunks along S
#define CLEN 128                // steps per chunk (NCHUNK*CLEN == SEQ)

typedef unsigned short u16;
typedef __attribute__((ext_vector_type(8))) short short8;   // 8 x bf16 MFMA frag
typedef __attribute__((ext_vector_type(4))) float floatx4;  // MFMA acc

// ---- bf16 helpers (bit-level, RNE) ----
__device__ __forceinline__ float bflo(uint32_t u) { return __uint_as_float(u << 16); }
__device__ __forceinline__ float bfhi(uint32_t u) { return __uint_as_float(u & 0xffff0000u); }
__device__ __forceinline__ uint32_t f2bf_bits(float f) {
    uint32_t u = __float_as_uint(f);
    return (u + 0x7fffu + ((u >> 16) & 1u)) >> 16;  // round-to-nearest-even
}

// ============================================================
// cast fp32 -> bf16 (vectorized, grid-stride)
// ============================================================
__global__ __launch_bounds__(256) void cast_f32_bf16(const float* __restrict__ in,
                                                     u16* __restrict__ out, int n4) {
    int i = blockIdx.x * blockDim.x + threadIdx.x;
    int stride = gridDim.x * blockDim.x;
    const float4* in4 = (const float4*)in;
    ushort4* out4 = (ushort4*)out;
    for (; i < n4; i += stride) {
        float4 v = in4[i];
        ushort4 o;
        o.x = (u16)f2bf_bits(v.x);
        o.y = (u16)f2bf_bits(v.y);
        o.z = (u16)f2bf_bits(v.z);
        o.w = (u16)f2bf_bits(v.w);
        out4[i] = o;
    }
}

// ============================================================
// transpose + cast: in[R][C] fp32 -> out[C][R] bf16   (64x64 tiles)
// ============================================================
__global__ __launch_bounds__(1024) void transpose_cast(const float* __restrict__ in,
                                                       u16* __restrict__ out, int R, int C) {
    __shared__ float tile[64][65];
    int c0 = blockIdx.x * 64, r0 = blockIdx.y * 64;
    int tx = threadIdx.x, ty = threadIdx.y;
#pragma unroll
    for (int i = ty; i < 64; i += 16)
        tile[i][tx] = in[(size_t)(r0 + i) * C + c0 + tx];
    __syncthreads();
#pragma unroll
    for (int i = ty; i < 64; i += 16)
        out[(size_t)(c0 + i) * R + r0 + tx] = (u16)f2bf_bits(tile[tx][i]);
}

// ============================================================
// bf16 MFMA GEMM: C[M][N] = A[M][K] * B[K][N],  B given transposed as Bt[N][K].
// 128x128 block tile, BK=32, 256 threads (4 waves, each 64x64 = 4x4 MFMA tiles).
// global_load_lds width-16 staging.
//
// LDS XOR swizzle (bank-conflict fix): LDS slot (row, pos) holds global
// k-block (pos ^ ((row>>1)&3)).  global_load_lds pins lane i -> slot i*16B,
// so the swizzle is applied on the gather side (staging lane fetches the
// permuted global block) and mirrored in the fragment-read address.
// Swizzle term depends only on (row>>1)&3; wave/i row offsets are multiples
// of 4 rows so it is wave-uniform at store time.  Read pattern becomes
// 2 lanes per 4-bank group per quarter-wave (2-way = free, m136).
// ============================================================
template <int OUT_BF16>
__global__ __launch_bounds__(256, 2) void gemm_bf16(const u16* __restrict__ A,
                                                    const u16* __restrict__ Bt,
                                                    void* __restrict__ C,
                                                    const int M, const int N, const int K) {
    __shared__ alignas(16) u16 As[128 * 32];  // [m][k-swizzled], row stride 32 elems (64B)
    __shared__ alignas(16) u16 Bs[128 * 32];  // [n][k-swizzled]

    const int tid = threadIdx.x;
    const int lane = tid & 63;
    const int wave = tid >> 6;            // 0..3
    const int wm = (wave >> 1) * 64;      // wave offset in block tile (rows)
    const int wn = (wave & 1) * 64;       // (cols)
    const size_t m0 = (size_t)blockIdx.y * 128;
    const size_t n0 = (size_t)blockIdx.x * 128;

    floatx4 acc[4][4];
#pragma unroll
    for (int i = 0; i < 4; ++i)
#pragma unroll
        for (int j = 0; j < 4; ++j) acc[i][j] = (floatx4){0.f, 0.f, 0.f, 0.f};

    // staging: one wave-issue covers 16 rows x 32 cols bf16 (16 rows x 64B)
    const int srow = lane >> 2;                                // 0..15 row within issue
    const int scol = ((lane & 3) ^ ((srow >> 1) & 3)) * 8;     // swizzled k-block (elems)
    const u16* Ag = A + m0 * K + (size_t)(wave * 16 + srow) * K + scol;
    const u16* Bg = Bt + n0 * K + (size_t)(wave * 16 + srow) * K + scol;
    u16* Asw = As + (wave * 16) * 32;  // wave-uniform LDS bases
    u16* Bsw = Bs + (wave * 16) * 32;

    const int fr = lane & 15;          // fragment row/col within 16
    const int kblk = lane >> 4;        // k-block 0..3
    const int koff = (kblk ^ ((fr >> 1) & 3)) * 8;  // swizzled read offset (elems)

    for (int k0 = 0; k0 < K; k0 += 32) {
        __syncthreads();
#pragma unroll
        for (int i = 0; i < 2; ++i) {
            __builtin_amdgcn_global_load_lds(
                (const __attribute__((address_space(1))) uint32_t*)(const void*)(Ag + (size_t)i * 64 * K + k0),
                (__attribute__((address_space(3))) uint32_t*)(void*)(Asw + i * 64 * 32),
                16, 0, 0);
            __builtin_amdgcn_global_load_lds(
                (const __attribute__((address_space(1))) uint32_t*)(const void*)(Bg + (size_t)i * 64 * K + k0),
                (__attribute__((address_space(3))) uint32_t*)(void*)(Bsw + i * 64 * 32),
                16, 0, 0);
        }
        __syncthreads();

        short8 af[4], bfr[4];
#pragma unroll
        for (int i = 0; i < 4; ++i)
            af[i] = *(const short8*)(As + (wm + i * 16 + fr) * 32 + koff);
#pragma unroll
        for (int j = 0; j < 4; ++j)
            bfr[j] = *(const short8*)(Bs + (wn + j * 16 + fr) * 32 + koff);
#pragma unroll
        for (int i = 0; i < 4; ++i)
#pragma unroll
            for (int j = 0; j < 4; ++j)
                acc[i][j] = __builtin_amdgcn_mfma_f32_16x16x32_bf16(af[i], bfr[j], acc[i][j], 0, 0, 0);
    }

    // epilogue: C/D layout col = lane&15, row = (lane>>4)*4 + reg
    const int r0row = (lane >> 4) * 4;
#pragma unroll
    for (int i = 0; i < 4; ++i) {
#pragma unroll
        for (int r = 0; r < 4; ++r) {
            size_t row = m0 + wm + i * 16 + r0row + r;
#pragma unroll
            for (int j = 0; j < 4; ++j) {
                size_t col = n0 + wn + j * 16 + fr;
                float v = acc[i][j][r];
                if (OUT_BF16)
                    ((u16*)C)[row * N + col] = (u16)f2bf_bits(v);
                else
                    ((float*)C)[row * N + col] = v;
            }
        }
    }
}

// ============================================================
// scan helpers: per element  a = sigmoid(-g), v = sigmoid(g)*(relu(h)+0.5)
// recurrence h_t = a_t * h_{t-1} + v_t   (== reference log-space scan)
// hg layout: u16[M][4096], hidden at col c (<2048), gate at 2048+c.
// Each thread handles a PAIR of channels (uint32 loads).
// ============================================================
__device__ __forceinline__ void av_pair(uint32_t hh, uint32_t gg,
                                        float& a0, float& v0, float& a1, float& v1) {
    float h0 = bflo(hh), h1 = bfhi(hh);
    float g0 = bflo(gg), g1 = bfhi(gg);
    g0 = fminf(fmaxf(g0, -30.f), 30.f);
    g1 = fminf(fmaxf(g1, -30.f), 30.f);
    float e0 = __expf(-g0), e1 = __expf(-g1);
    float z0 = 1.f / (1.f + e0), z1 = 1.f / (1.f + e1);
    a0 = e0 * z0;  // sigmoid(-g) = 1 - z
    a1 = e1 * z1;
    v0 = z0 * (fmaxf(h0, 0.f) + 0.5f);
    v1 = z1 * (fmaxf(h1, 0.f) + 0.5f);
}

// Phase A: per-chunk affine summary (A = prod a, V = chunk result from h_in=0)
__global__ __launch_bounds__(256) void scan_chunks(const uint32_t* __restrict__ hg,
                                                   float2* __restrict__ sumAV) {
    const int b = blockIdx.z, ch = blockIdx.y;
    const int cp = blockIdx.x * 256 + threadIdx.x;  // channel-pair 0..1023
    const size_t rowbase = (size_t)b * SEQ + (size_t)ch * CLEN;
    float A0 = 1.f, V0 = 0.f, A1 = 1.f, V1 = 0.f;
    for (int j = 0; j < CLEN; ++j) {
        size_t row = rowbase + j;
        uint32_t hh = hg[row * 2048 + cp];
        uint32_t gg = hg[row * 2048 + 1024 + cp];
        float a0, v0, a1, v1;
        av_pair(hh, gg, a0, v0, a1, v1);
        V0 = fmaf(a0, V0, v0); A0 *= a0;
        V1 = fmaf(a1, V1, v1); A1 *= a1;
    }
    ((float4*)sumAV)[(size_t)(b * NCHUNK + ch) * 1024 + cp] = (float4){A0, V0, A1, V1};
}

// Phase B: sequential carry scan over the 32 chunk summaries per chain
__global__ __launch_bounds__(256) void scan_carry(const float2* __restrict__ sumAV,
                                                  float* __restrict__ carry) {
    const int b = blockIdx.y;
    const int c = blockIdx.x * 256 + threadIdx.x;  // chain channel 0..2047
    float2 s[NCHUNK];
#pragma unroll
    for (int ch = 0; ch < NCHUNK; ++ch)
        s[ch] = sumAV[(size_t)(b * NCHUNK + ch) * 2048 + c];
    float h = 0.f;
#pragma unroll
    for (int ch = 0; ch < NCHUNK; ++ch) {
        carry[(size_t)(b * NCHUNK + ch) * 2048 + c] = h;
        h = fmaf(s[ch].x, h, s[ch].y);
    }
}

// Phase C: replay chunk with carry-in, emit h as bf16
__global__ __launch_bounds__(256) void scan_apply(const uint32_t* __restrict__ hg,
                                                  const float* __restrict__ carry,
                                                  uint32_t* __restrict__ hbuf) {
    const int b = blockIdx.z, ch = blockIdx.y;
    const int cp = blockIdx.x * 256 + threadIdx.x;
    const size_t rowbase = (size_t)b * SEQ + (size_t)ch * CLEN;
    const float2 c2 = ((const float2*)carry)[(size_t)(b * NCHUNK + ch) * 1024 + cp];
    float h0 = c2.x, h1 = c2.y;
    for (int j = 0; j < CLEN; ++j) {
        size_t row = rowbase + j;
        uint32_t hh = hg[row * 2048 + cp];
        uint32_t gg = hg[row * 2048 + 1024 + cp];
        float a0, v0, a1, v1;
        av_pair(hh, gg, a0, v0, a1, v1);
        h0 = fmaf(a0, h0, v0);
        h1 = fmaf(a1, h1, v1);
        hbuf[row * 1024 + cp] = f2bf_bits(h0) | (f2bf_bits(h1) << 16);
    }
}

// ============================================================
extern "C" void kernel_launch(void* const* d_in, const int* in_sizes, int n_in,
                              void* d_out, int out_size, void* d_ws, size_t ws_size,
                              hipStream_t stream) {
    const float* x = (const float*)d_in[0];     // [16384,1024]
    const float* Whg = (const float*)d_in[1];   // [1024,4096]
    const float* Wout = (const float*)d_in[2];  // [2048,1024]

    char* ws = (char*)d_ws;
    size_t off = 0;
    u16* xb = (u16*)(ws + off);        off += (size_t)M_TOTAL * DIMX * 2;        // 32 MB
    u16* whgt = (u16*)(ws + off);      off += (size_t)N_HG * DIMX * 2;           // 8 MB
    u16* woutt = (u16*)(ws + off);     off += (size_t)DIMX * DIM_INNER * 2;      // 4 MB
    u16* hg = (u16*)(ws + off);        off += (size_t)M_TOTAL * N_HG * 2;        // 128 MB
    uint32_t* hbuf = (uint32_t*)(ws + off); off += (size_t)M_TOTAL * DIM_INNER * 2; // 64 MB
    float2* sumAV = (float2*)(ws + off); off += (size_t)BATCH * NCHUNK * DIM_INNER * 8; // 2 MB
    float* carry = (float*)(ws + off);  off += (size_t)BATCH * NCHUNK * DIM_INNER * 4; // 1 MB

    // 1. casts / transposes
    cast_f32_bf16<<<2048, 256, 0, stream>>>(x, xb, M_TOTAL * DIMX / 4);
    transpose_cast<<<dim3(N_HG / 64, DIMX / 64), dim3(64, 16), 0, stream>>>(Whg, whgt, DIMX, N_HG);
    transpose_cast<<<dim3(DIMX / 64, DIM_INNER / 64), dim3(64, 16), 0, stream>>>(Wout, woutt, DIM_INNER, DIMX);

    // 2. GEMM1: hg[16384][4096] = xb @ Whg   (bf16 out)
    gemm_bf16<1><<<dim3(N_HG / 128, M_TOTAL / 128), 256, 0, stream>>>(xb, whgt, hg, M_TOTAL, N_HG, DIMX);

    // 3. chunked scan over S
    scan_chunks<<<dim3(4, NCHUNK, BATCH), 256, 0, stream>>>((const uint32_t*)hg, sumAV);
    scan_carry<<<dim3(8, BATCH), 256, 0, stream>>>(sumAV, carry);
    scan_apply<<<dim3(4, NCHUNK, BATCH), 256, 0, stream>>>((const uint32_t*)hg, carry, hbuf);

    // 4. GEMM2: out[16384][1024] = h @ Wout  (fp32 out)
    gemm_bf16<0><<<dim3(DIMX / 128, M_TOTAL / 128), 256, 0, stream>>>((const u16*)hbuf, woutt, d_out, M_TOTAL, DIMX, DIM_INNER);
}

// Round 4
// 458.494 us; speedup vs baseline: 1.0572x; 1.0393x over previous
//
#include <hip/hip_runtime.h>
#include <stdint.h>

// ---- problem constants ----
#define DIMX 1024
#define DIM_INNER 2048
#define BATCH 4
#define SEQ 4096
#define M_TOTAL (BATCH * SEQ)   // 16384
#define N_HG (2 * DIM_INNER)    // 4096
#define NCHUNK 128              // chunks along S
#define CLEN 32                 // steps per chunk (NCHUNK*CLEN == SEQ)

typedef unsigned short u16;
typedef __attribute__((ext_vector_type(8))) short short8;   // 8 x bf16 MFMA frag
typedef __attribute__((ext_vector_type(4))) float floatx4;  // MFMA acc

// ---- bf16 helpers (bit-level, RNE) ----
__device__ __forceinline__ float bflo(uint32_t u) { return __uint_as_float(u << 16); }
__device__ __forceinline__ float bfhi(uint32_t u) { return __uint_as_float(u & 0xffff0000u); }
__device__ __forceinline__ uint32_t f2bf_bits(float f) {
    uint32_t u = __float_as_uint(f);
    return (u + 0x7fffu + ((u >> 16) & 1u)) >> 16;  // round-to-nearest-even
}

// ============================================================
// cast fp32 -> bf16 (vectorized, grid-stride)
// ============================================================
__global__ __launch_bounds__(256) void cast_f32_bf16(const float* __restrict__ in,
                                                     u16* __restrict__ out, int n4) {
    int i = blockIdx.x * blockDim.x + threadIdx.x;
    int stride = gridDim.x * blockDim.x;
    const float4* in4 = (const float4*)in;
    ushort4* out4 = (ushort4*)out;
    for (; i < n4; i += stride) {
        float4 v = in4[i];
        ushort4 o;
        o.x = (u16)f2bf_bits(v.x);
        o.y = (u16)f2bf_bits(v.y);
        o.z = (u16)f2bf_bits(v.z);
        o.w = (u16)f2bf_bits(v.w);
        out4[i] = o;
    }
}

// ============================================================
// transpose + cast: in[R][C] fp32 -> out[C][R] bf16   (64x64 tiles)
// ============================================================
__global__ __launch_bounds__(1024) void transpose_cast(const float* __restrict__ in,
                                                       u16* __restrict__ out, int R, int C) {
    __shared__ float tile[64][65];
    int c0 = blockIdx.x * 64, r0 = blockIdx.y * 64;
    int tx = threadIdx.x, ty = threadIdx.y;
#pragma unroll
    for (int i = ty; i < 64; i += 16)
        tile[i][tx] = in[(size_t)(r0 + i) * C + c0 + tx];
    __syncthreads();
#pragma unroll
    for (int i = ty; i < 64; i += 16)
        out[(size_t)(c0 + i) * R + r0 + tx] = (u16)f2bf_bits(tile[tx][i]);
}

// ============================================================
// bf16 MFMA GEMM: C[M][N] = A[M][K] * B[K][N],  B given transposed as Bt[N][K].
// 128x128 block tile, BK=32, 256 threads (4 waves, each 64x64 = 4x4 MFMA tiles).
// global_load_lds width-16 staging + XOR k-block swizzle (R3: conflicts -> 0).
// ============================================================
template <int OUT_BF16>
__global__ __launch_bounds__(256, 2) void gemm_bf16(const u16* __restrict__ A,
                                                    const u16* __restrict__ Bt,
                                                    void* __restrict__ C,
                                                    const int M, const int N, const int K) {
    __shared__ alignas(16) u16 As[128 * 32];  // [m][k-swizzled], row stride 32 elems (64B)
    __shared__ alignas(16) u16 Bs[128 * 32];  // [n][k-swizzled]

    const int tid = threadIdx.x;
    const int lane = tid & 63;
    const int wave = tid >> 6;            // 0..3
    const int wm = (wave >> 1) * 64;      // wave offset in block tile (rows)
    const int wn = (wave & 1) * 64;       // (cols)
    const size_t m0 = (size_t)blockIdx.y * 128;
    const size_t n0 = (size_t)blockIdx.x * 128;

    floatx4 acc[4][4];
#pragma unroll
    for (int i = 0; i < 4; ++i)
#pragma unroll
        for (int j = 0; j < 4; ++j) acc[i][j] = (floatx4){0.f, 0.f, 0.f, 0.f};

    // staging: one wave-issue covers 16 rows x 32 cols bf16 (16 rows x 64B)
    const int srow = lane >> 2;                                // 0..15 row within issue
    const int scol = ((lane & 3) ^ ((srow >> 1) & 3)) * 8;     // swizzled k-block (elems)
    const u16* Ag = A + m0 * K + (size_t)(wave * 16 + srow) * K + scol;
    const u16* Bg = Bt + n0 * K + (size_t)(wave * 16 + srow) * K + scol;
    u16* Asw = As + (wave * 16) * 32;  // wave-uniform LDS bases
    u16* Bsw = Bs + (wave * 16) * 32;

    const int fr = lane & 15;          // fragment row/col within 16
    const int kblk = lane >> 4;        // k-block 0..3
    const int koff = (kblk ^ ((fr >> 1) & 3)) * 8;  // swizzled read offset (elems)

    for (int k0 = 0; k0 < K; k0 += 32) {
        __syncthreads();
#pragma unroll
        for (int i = 0; i < 2; ++i) {
            __builtin_amdgcn_global_load_lds(
                (const __attribute__((address_space(1))) uint32_t*)(const void*)(Ag + (size_t)i * 64 * K + k0),
                (__attribute__((address_space(3))) uint32_t*)(void*)(Asw + i * 64 * 32),
                16, 0, 0);
            __builtin_amdgcn_global_load_lds(
                (const __attribute__((address_space(1))) uint32_t*)(const void*)(Bg + (size_t)i * 64 * K + k0),
                (__attribute__((address_space(3))) uint32_t*)(void*)(Bsw + i * 64 * 32),
                16, 0, 0);
        }
        __syncthreads();

        short8 af[4], bfr[4];
#pragma unroll
        for (int i = 0; i < 4; ++i)
            af[i] = *(const short8*)(As + (wm + i * 16 + fr) * 32 + koff);
#pragma unroll
        for (int j = 0; j < 4; ++j)
            bfr[j] = *(const short8*)(Bs + (wn + j * 16 + fr) * 32 + koff);
#pragma unroll
        for (int i = 0; i < 4; ++i)
#pragma unroll
            for (int j = 0; j < 4; ++j)
                acc[i][j] = __builtin_amdgcn_mfma_f32_16x16x32_bf16(af[i], bfr[j], acc[i][j], 0, 0, 0);
    }

    // epilogue: C/D layout col = lane&15, row = (lane>>4)*4 + reg
    const int r0row = (lane >> 4) * 4;
#pragma unroll
    for (int i = 0; i < 4; ++i) {
#pragma unroll
        for (int r = 0; r < 4; ++r) {
            size_t row = m0 + wm + i * 16 + r0row + r;
#pragma unroll
            for (int j = 0; j < 4; ++j) {
                size_t col = n0 + wn + j * 16 + fr;
                float v = acc[i][j][r];
                if (OUT_BF16)
                    ((u16*)C)[row * N + col] = (u16)f2bf_bits(v);
                else
                    ((float*)C)[row * N + col] = v;
            }
        }
    }
}

// ============================================================
// scan: per element  a = sigmoid(-g), v = sigmoid(g)*(relu(h)+0.5)
// recurrence h_t = a_t * h_{t-1} + v_t   (== reference log-space scan)
// hg layout: u16[M][4096], hidden at col c (<2048), gate at 2048+c.
// Each thread handles FOUR channels (uint2 = 8B loads), prefetched.
// ============================================================
__device__ __forceinline__ void av_pair(uint32_t hh, uint32_t gg,
                                        float& a0, float& v0, float& a1, float& v1) {
    float h0 = bflo(hh), h1 = bfhi(hh);
    float g0 = bflo(gg), g1 = bfhi(gg);
    g0 = fminf(fmaxf(g0, -30.f), 30.f);
    g1 = fminf(fmaxf(g1, -30.f), 30.f);
    float e0 = __expf(-g0), e1 = __expf(-g1);
    float z0 = 1.f / (1.f + e0), z1 = 1.f / (1.f + e1);
    a0 = e0 * z0;  // sigmoid(-g) = 1 - z
    a1 = e1 * z1;
    v0 = z0 * (fmaxf(h0, 0.f) + 0.5f);
    v1 = z1 * (fmaxf(h1, 0.f) + 0.5f);
}

// Phase A: per-chunk affine summary (A = prod a, V = chunk result from h_in=0)
// grid (2, NCHUNK, BATCH) x 256 thr; thread -> channel-quad cq (4 channels)
__global__ __launch_bounds__(256) void scan_chunks(const u16* __restrict__ hg,
                                                   float2* __restrict__ sumAV) {
    const int b = blockIdx.z, ch = blockIdx.y;
    const int cq = blockIdx.x * 256 + threadIdx.x;  // 0..511
    const int c4 = cq * 4;
    const size_t rowbase = (size_t)b * SEQ + (size_t)ch * CLEN;
    float A[4] = {1.f, 1.f, 1.f, 1.f}, V[4] = {0.f, 0.f, 0.f, 0.f};
    uint2 hh = *(const uint2*)(hg + rowbase * 4096 + c4);
    uint2 gg = *(const uint2*)(hg + rowbase * 4096 + 2048 + c4);
#pragma unroll 4
    for (int j = 0; j < CLEN; ++j) {
        uint2 hn, gn;
        if (j + 1 < CLEN) {
            hn = *(const uint2*)(hg + (rowbase + j + 1) * 4096 + c4);
            gn = *(const uint2*)(hg + (rowbase + j + 1) * 4096 + 2048 + c4);
        }
        float a0, v0, a1, v1, a2, v2, a3, v3;
        av_pair(hh.x, gg.x, a0, v0, a1, v1);
        av_pair(hh.y, gg.y, a2, v2, a3, v3);
        V[0] = fmaf(a0, V[0], v0); A[0] *= a0;
        V[1] = fmaf(a1, V[1], v1); A[1] *= a1;
        V[2] = fmaf(a2, V[2], v2); A[2] *= a2;
        V[3] = fmaf(a3, V[3], v3); A[3] *= a3;
        hh = hn; gg = gn;
    }
    float4* dst = (float4*)(sumAV + (size_t)(b * NCHUNK + ch) * 2048 + c4);
    dst[0] = (float4){A[0], V[0], A[1], V[1]};
    dst[1] = (float4){A[2], V[2], A[3], V[3]};
}

// Phase B: sequential carry scan over NCHUNK chunk summaries per chain
// one thread per (b, channel): 32 blocks x 256
__global__ __launch_bounds__(256) void scan_carry(const float2* __restrict__ sumAV,
                                                  float* __restrict__ carry) {
    const int g = blockIdx.x * 256 + threadIdx.x;  // 0..8191
    const int b = g >> 11, c = g & 2047;
    float h = 0.f;
#pragma unroll 8
    for (int ch = 0; ch < NCHUNK; ++ch) {
        float2 s = sumAV[(size_t)(b * NCHUNK + ch) * 2048 + c];
        carry[(size_t)(b * NCHUNK + ch) * 2048 + c] = h;
        h = fmaf(s.x, h, s.y);
    }
}

// Phase C: replay chunk with carry-in, emit h as bf16
__global__ __launch_bounds__(256) void scan_apply(const u16* __restrict__ hg,
                                                  const float* __restrict__ carry,
                                                  uint32_t* __restrict__ hbuf) {
    const int b = blockIdx.z, ch = blockIdx.y;
    const int cq = blockIdx.x * 256 + threadIdx.x;
    const int c4 = cq * 4;
    const size_t rowbase = (size_t)b * SEQ + (size_t)ch * CLEN;
    float4 cin = *(const float4*)(carry + (size_t)(b * NCHUNK + ch) * 2048 + c4);
    float h0 = cin.x, h1 = cin.y, h2 = cin.z, h3 = cin.w;
    uint2 hh = *(const uint2*)(hg + rowbase * 4096 + c4);
    uint2 gg = *(const uint2*)(hg + rowbase * 4096 + 2048 + c4);
#pragma unroll 4
    for (int j = 0; j < CLEN; ++j) {
        uint2 hn, gn;
        if (j + 1 < CLEN) {
            hn = *(const uint2*)(hg + (rowbase + j + 1) * 4096 + c4);
            gn = *(const uint2*)(hg + (rowbase + j + 1) * 4096 + 2048 + c4);
        }
        float a0, v0, a1, v1, a2, v2, a3, v3;
        av_pair(hh.x, gg.x, a0, v0, a1, v1);
        av_pair(hh.y, gg.y, a2, v2, a3, v3);
        h0 = fmaf(a0, h0, v0);
        h1 = fmaf(a1, h1, v1);
        h2 = fmaf(a2, h2, v2);
        h3 = fmaf(a3, h3, v3);
        uint2 o;
        o.x = f2bf_bits(h0) | (f2bf_bits(h1) << 16);
        o.y = f2bf_bits(h2) | (f2bf_bits(h3) << 16);
        *(uint2*)(hbuf + (rowbase + j) * 1024 + cq * 2) = o;
        hh = hn; gg = gn;
    }
}

// ============================================================
extern "C" void kernel_launch(void* const* d_in, const int* in_sizes, int n_in,
                              void* d_out, int out_size, void* d_ws, size_t ws_size,
                              hipStream_t stream) {
    const float* x = (const float*)d_in[0];     // [16384,1024]
    const float* Whg = (const float*)d_in[1];   // [1024,4096]
    const float* Wout = (const float*)d_in[2];  // [2048,1024]

    char* ws = (char*)d_ws;
    size_t off = 0;
    u16* xb = (u16*)(ws + off);        off += (size_t)M_TOTAL * DIMX * 2;        // 32 MB
    u16* whgt = (u16*)(ws + off);      off += (size_t)N_HG * DIMX * 2;           // 8 MB
    u16* woutt = (u16*)(ws + off);     off += (size_t)DIMX * DIM_INNER * 2;      // 4 MB
    u16* hg = (u16*)(ws + off);        off += (size_t)M_TOTAL * N_HG * 2;        // 128 MB
    uint32_t* hbuf = (uint32_t*)(ws + off); off += (size_t)M_TOTAL * DIM_INNER * 2; // 64 MB
    // sumAV (8 MB) + carry (4 MB) alias xb's region: xb is dead after GEMM1,
    // and GEMM1 completes before scan_chunks on the same stream.
    float2* sumAV = (float2*)(ws + 0);
    float* carry = (float*)(ws + (size_t)BATCH * NCHUNK * DIM_INNER * 8);

    // 1. casts / transposes
    cast_f32_bf16<<<2048, 256, 0, stream>>>(x, xb, M_TOTAL * DIMX / 4);
    transpose_cast<<<dim3(N_HG / 64, DIMX / 64), dim3(64, 16), 0, stream>>>(Whg, whgt, DIMX, N_HG);
    transpose_cast<<<dim3(DIMX / 64, DIM_INNER / 64), dim3(64, 16), 0, stream>>>(Wout, woutt, DIM_INNER, DIMX);

    // 2. GEMM1: hg[16384][4096] = xb @ Whg   (bf16 out)
    gemm_bf16<1><<<dim3(N_HG / 128, M_TOTAL / 128), 256, 0, stream>>>(xb, whgt, hg, M_TOTAL, N_HG, DIMX);

    // 3. chunked scan over S
    scan_chunks<<<dim3(2, NCHUNK, BATCH), 256, 0, stream>>>(hg, sumAV);
    scan_carry<<<dim3(32), 256, 0, stream>>>(sumAV, carry);
    scan_apply<<<dim3(2, NCHUNK, BATCH), 256, 0, stream>>>(hg, carry, hbuf);

    // 4. GEMM2: out[16384][1024] = h @ Wout  (fp32 out)
    gemm_bf16<0><<<dim3(DIMX / 128, M_TOTAL / 128), 256, 0, stream>>>((const u16*)hbuf, woutt, d_out, M_TOTAL, DIMX, DIM_INNER);
}

// Round 5
// 452.268 us; speedup vs baseline: 1.0718x; 1.0138x over previous
//
#include <hip/hip_runtime.h>
#include <stdint.h>

// ---- problem constants ----
#define DIMX 1024
#define DIM_INNER 2048
#define BATCH 4
#define SEQ 4096
#define M_TOTAL (BATCH * SEQ)   // 16384
#define N_HG (2 * DIM_INNER)    // 4096
#define NCHUNK 128              // chunks along S
#define CLEN 32                 // steps per chunk (NCHUNK*CLEN == SEQ)

typedef unsigned short u16;
typedef __attribute__((ext_vector_type(8))) short short8;   // 8 x bf16 MFMA frag
typedef __attribute__((ext_vector_type(4))) float floatx4;  // MFMA acc

// ---- bf16 helpers (bit-level, RNE) ----
__device__ __forceinline__ float bflo(uint32_t u) { return __uint_as_float(u << 16); }
__device__ __forceinline__ float bfhi(uint32_t u) { return __uint_as_float(u & 0xffff0000u); }
__device__ __forceinline__ uint32_t f2bf_bits(float f) {
    uint32_t u = __float_as_uint(f);
    return (u + 0x7fffu + ((u >> 16) & 1u)) >> 16;  // round-to-nearest-even
}

// ============================================================
// prep kernel: fuses x-cast + Whg transpose + Wout transpose.
//   blocks [0,2048)            : cast x fp32 -> bf16 (grid-stride)
//   blocks [2048, 2048+1024)   : Whg  [1024][4096] -> whgt  [4096][1024] bf16
//   blocks [3072, 3072+512)    : Wout [2048][1024] -> woutt [1024][2048] bf16
// 256 threads/block everywhere.
// ============================================================
__global__ __launch_bounds__(256) void prep(const float* __restrict__ x,
                                            const float* __restrict__ Whg,
                                            const float* __restrict__ Wout,
                                            u16* __restrict__ xb,
                                            u16* __restrict__ whgt,
                                            u16* __restrict__ woutt) {
    __shared__ float tile[64][65];
    const int bid = blockIdx.x;
    const int tid = threadIdx.x;
    if (bid < 2048) {
        // cast: n4 = M_TOTAL*DIMX/4 float4 elements
        const int n4 = M_TOTAL * DIMX / 4;
        const float4* in4 = (const float4*)x;
        ushort4* out4 = (ushort4*)xb;
        for (int i = bid * 256 + tid; i < n4; i += 2048 * 256) {
            float4 v = in4[i];
            ushort4 o;
            o.x = (u16)f2bf_bits(v.x);
            o.y = (u16)f2bf_bits(v.y);
            o.z = (u16)f2bf_bits(v.z);
            o.w = (u16)f2bf_bits(v.w);
            out4[i] = o;
        }
        return;
    }
    // transpose phase: pick source
    const float* in;
    u16* out;
    int R, C, tb;
    if (bid < 3072) {
        in = Whg; out = whgt; R = DIMX; C = N_HG; tb = bid - 2048;   // 64 x 16 tiles
    } else {
        in = Wout; out = woutt; R = DIM_INNER; C = DIMX; tb = bid - 3072;  // 16 x 32 tiles
    }
    const int tilesx = C / 64;
    const int c0 = (tb % tilesx) * 64, r0 = (tb / tilesx) * 64;
    const int tx = tid & 63, ty = tid >> 6;  // 64 x 4
#pragma unroll
    for (int i = ty; i < 64; i += 4)
        tile[i][tx] = in[(size_t)(r0 + i) * C + c0 + tx];
    __syncthreads();
#pragma unroll
    for (int i = ty; i < 64; i += 4)
        out[(size_t)(c0 + i) * R + r0 + tx] = (u16)f2bf_bits(tile[tx][i]);
}

// ============================================================
// bf16 MFMA GEMM: C[M][N] = A[M][K] * B[K][N],  B given transposed as Bt[N][K].
// 128x128 block tile, BK=32, 256 threads (4 waves, each 64x64 = 4x4 MFMA tiles).
// global_load_lds width-16 staging + XOR k-block swizzle (R3: conflicts -> 0).
// ============================================================
template <int OUT_BF16>
__global__ __launch_bounds__(256, 2) void gemm_bf16(const u16* __restrict__ A,
                                                    const u16* __restrict__ Bt,
                                                    void* __restrict__ C,
                                                    const int M, const int N, const int K) {
    __shared__ alignas(16) u16 As[128 * 32];  // [m][k-swizzled], row stride 32 elems (64B)
    __shared__ alignas(16) u16 Bs[128 * 32];  // [n][k-swizzled]

    const int tid = threadIdx.x;
    const int lane = tid & 63;
    const int wave = tid >> 6;            // 0..3
    const int wm = (wave >> 1) * 64;      // wave offset in block tile (rows)
    const int wn = (wave & 1) * 64;       // (cols)
    const size_t m0 = (size_t)blockIdx.y * 128;
    const size_t n0 = (size_t)blockIdx.x * 128;

    floatx4 acc[4][4];
#pragma unroll
    for (int i = 0; i < 4; ++i)
#pragma unroll
        for (int j = 0; j < 4; ++j) acc[i][j] = (floatx4){0.f, 0.f, 0.f, 0.f};

    // staging: one wave-issue covers 16 rows x 32 cols bf16 (16 rows x 64B)
    const int srow = lane >> 2;                                // 0..15 row within issue
    const int scol = ((lane & 3) ^ ((srow >> 1) & 3)) * 8;     // swizzled k-block (elems)
    const u16* Ag = A + m0 * K + (size_t)(wave * 16 + srow) * K + scol;
    const u16* Bg = Bt + n0 * K + (size_t)(wave * 16 + srow) * K + scol;
    u16* Asw = As + (wave * 16) * 32;  // wave-uniform LDS bases
    u16* Bsw = Bs + (wave * 16) * 32;

    const int fr = lane & 15;          // fragment row/col within 16
    const int kblk = lane >> 4;        // k-block 0..3
    const int koff = (kblk ^ ((fr >> 1) & 3)) * 8;  // swizzled read offset (elems)

    for (int k0 = 0; k0 < K; k0 += 32) {
        __syncthreads();
#pragma unroll
        for (int i = 0; i < 2; ++i) {
            __builtin_amdgcn_global_load_lds(
                (const __attribute__((address_space(1))) uint32_t*)(const void*)(Ag + (size_t)i * 64 * K + k0),
                (__attribute__((address_space(3))) uint32_t*)(void*)(Asw + i * 64 * 32),
                16, 0, 0);
            __builtin_amdgcn_global_load_lds(
                (const __attribute__((address_space(1))) uint32_t*)(const void*)(Bg + (size_t)i * 64 * K + k0),
                (__attribute__((address_space(3))) uint32_t*)(void*)(Bsw + i * 64 * 32),
                16, 0, 0);
        }
        __syncthreads();

        short8 af[4], bfr[4];
#pragma unroll
        for (int i = 0; i < 4; ++i)
            af[i] = *(const short8*)(As + (wm + i * 16 + fr) * 32 + koff);
#pragma unroll
        for (int j = 0; j < 4; ++j)
            bfr[j] = *(const short8*)(Bs + (wn + j * 16 + fr) * 32 + koff);
#pragma unroll
        for (int i = 0; i < 4; ++i)
#pragma unroll
            for (int j = 0; j < 4; ++j)
                acc[i][j] = __builtin_amdgcn_mfma_f32_16x16x32_bf16(af[i], bfr[j], acc[i][j], 0, 0, 0);
    }

    // epilogue: C/D layout col = lane&15, row = (lane>>4)*4 + reg
    const int r0row = (lane >> 4) * 4;
#pragma unroll
    for (int i = 0; i < 4; ++i) {
#pragma unroll
        for (int r = 0; r < 4; ++r) {
            size_t row = m0 + wm + i * 16 + r0row + r;
#pragma unroll
            for (int j = 0; j < 4; ++j) {
                size_t col = n0 + wn + j * 16 + fr;
                float v = acc[i][j][r];
                if (OUT_BF16)
                    ((u16*)C)[row * N + col] = (u16)f2bf_bits(v);
                else
                    ((float*)C)[row * N + col] = v;
            }
        }
    }
}

// ============================================================
// scan: per element  a = sigmoid(-g), v = sigmoid(g)*(relu(h)+0.5)
// recurrence h_t = a_t * h_{t-1} + v_t   (== reference log-space scan)
// hg layout: u16[M][4096], hidden at col c (<2048), gate at 2048+c.
// Each thread handles EIGHT channels (uint4 = 16B loads), 2-row rolling
// prefetch -> 4 x 16B loads in flight per thread.
// ============================================================
__device__ __forceinline__ void av_pair(uint32_t hh, uint32_t gg,
                                        float& a0, float& v0, float& a1, float& v1) {
    float h0 = bflo(hh), h1 = bfhi(hh);
    float g0 = bflo(gg), g1 = bfhi(gg);
    g0 = fminf(fmaxf(g0, -30.f), 30.f);
    g1 = fminf(fmaxf(g1, -30.f), 30.f);
    float e0 = __expf(-g0), e1 = __expf(-g1);
    float z0 = 1.f / (1.f + e0), z1 = 1.f / (1.f + e1);
    a0 = e0 * z0;  // sigmoid(-g) = 1 - z
    a1 = e1 * z1;
    v0 = z0 * (fmaxf(h0, 0.f) + 0.5f);
    v1 = z1 * (fmaxf(h1, 0.f) + 0.5f);
}

__device__ __forceinline__ void av8(uint4 hh, uint4 gg, float* a, float* v) {
    av_pair(hh.x, gg.x, a[0], v[0], a[1], v[1]);
    av_pair(hh.y, gg.y, a[2], v[2], a[3], v[3]);
    av_pair(hh.z, gg.z, a[4], v[4], a[5], v[5]);
    av_pair(hh.w, gg.w, a[6], v[6], a[7], v[7]);
}

// Phase A: per-chunk affine summary. grid (NCHUNK, BATCH) x 256 thr.
// thread t -> channels [8t, 8t+8)
__global__ __launch_bounds__(256) void scan_chunks(const u16* __restrict__ hg,
                                                   float2* __restrict__ sumAV) {
    const int b = blockIdx.y, ch = blockIdx.x;
    const int c8 = threadIdx.x * 8;
    const size_t rowbase = (size_t)b * SEQ + (size_t)ch * CLEN;
    const u16* p = hg + rowbase * 4096 + c8;
    float A[8], V[8];
#pragma unroll
    for (int k = 0; k < 8; ++k) { A[k] = 1.f; V[k] = 0.f; }
    uint4 h0 = *(const uint4*)(p);
    uint4 g0 = *(const uint4*)(p + 2048);
    uint4 h1 = *(const uint4*)(p + 4096);
    uint4 g1 = *(const uint4*)(p + 4096 + 2048);
#pragma unroll 4
    for (int j = 0; j < CLEN; ++j) {
        uint4 h2, g2;
        if (j + 2 < CLEN) {
            h2 = *(const uint4*)(p + (size_t)(j + 2) * 4096);
            g2 = *(const uint4*)(p + (size_t)(j + 2) * 4096 + 2048);
        }
        float a[8], v[8];
        av8(h0, g0, a, v);
#pragma unroll
        for (int k = 0; k < 8; ++k) { V[k] = fmaf(a[k], V[k], v[k]); A[k] *= a[k]; }
        h0 = h1; g0 = g1; h1 = h2; g1 = g2;
    }
    float4* dst = (float4*)(sumAV + (size_t)(b * NCHUNK + ch) * 2048 + c8);
    dst[0] = (float4){A[0], V[0], A[1], V[1]};
    dst[1] = (float4){A[2], V[2], A[3], V[3]};
    dst[2] = (float4){A[4], V[4], A[5], V[5]};
    dst[3] = (float4){A[6], V[6], A[7], V[7]};
}

// Phase B: sequential carry scan over NCHUNK chunk summaries per chain.
// 128 blocks x 64 threads; thread -> one (b, channel) chain.
__global__ __launch_bounds__(64) void scan_carry(const float2* __restrict__ sumAV,
                                                 float* __restrict__ carry) {
    const int g = blockIdx.x * 64 + threadIdx.x;  // 0..8191
    const int b = g >> 11, c = g & 2047;
    float h = 0.f;
#pragma unroll 8
    for (int ch = 0; ch < NCHUNK; ++ch) {
        float2 s = sumAV[(size_t)(b * NCHUNK + ch) * 2048 + c];
        carry[(size_t)(b * NCHUNK + ch) * 2048 + c] = h;
        h = fmaf(s.x, h, s.y);
    }
}

// Phase C: replay chunk with carry-in, emit h as bf16 (uint4 stores).
__global__ __launch_bounds__(256) void scan_apply(const u16* __restrict__ hg,
                                                  const float* __restrict__ carry,
                                                  uint32_t* __restrict__ hbuf) {
    const int b = blockIdx.y, ch = blockIdx.x;
    const int c8 = threadIdx.x * 8;
    const size_t rowbase = (size_t)b * SEQ + (size_t)ch * CLEN;
    const u16* p = hg + rowbase * 4096 + c8;
    uint32_t* q = hbuf + rowbase * 1024 + c8 / 2;
    const float4* cin = (const float4*)(carry + (size_t)(b * NCHUNK + ch) * 2048 + c8);
    float4 cl = cin[0], chh = cin[1];
    float H[8] = {cl.x, cl.y, cl.z, cl.w, chh.x, chh.y, chh.z, chh.w};
    uint4 h0 = *(const uint4*)(p);
    uint4 g0 = *(const uint4*)(p + 2048);
    uint4 h1 = *(const uint4*)(p + 4096);
    uint4 g1 = *(const uint4*)(p + 4096 + 2048);
#pragma unroll 4
    for (int j = 0; j < CLEN; ++j) {
        uint4 h2, g2;
        if (j + 2 < CLEN) {
            h2 = *(const uint4*)(p + (size_t)(j + 2) * 4096);
            g2 = *(const uint4*)(p + (size_t)(j + 2) * 4096 + 2048);
        }
        float a[8], v[8];
        av8(h0, g0, a, v);
#pragma unroll
        for (int k = 0; k < 8; ++k) H[k] = fmaf(a[k], H[k], v[k]);
        uint4 o;
        o.x = f2bf_bits(H[0]) | (f2bf_bits(H[1]) << 16);
        o.y = f2bf_bits(H[2]) | (f2bf_bits(H[3]) << 16);
        o.z = f2bf_bits(H[4]) | (f2bf_bits(H[5]) << 16);
        o.w = f2bf_bits(H[6]) | (f2bf_bits(H[7]) << 16);
        *(uint4*)(q + (size_t)j * 1024) = o;
        h0 = h1; g0 = g1; h1 = h2; g1 = g2;
    }
}

// ============================================================
extern "C" void kernel_launch(void* const* d_in, const int* in_sizes, int n_in,
                              void* d_out, int out_size, void* d_ws, size_t ws_size,
                              hipStream_t stream) {
    const float* x = (const float*)d_in[0];     // [16384,1024]
    const float* Whg = (const float*)d_in[1];   // [1024,4096]
    const float* Wout = (const float*)d_in[2];  // [2048,1024]

    char* ws = (char*)d_ws;
    size_t off = 0;
    u16* xb = (u16*)(ws + off);        off += (size_t)M_TOTAL * DIMX * 2;        // 32 MB
    u16* whgt = (u16*)(ws + off);      off += (size_t)N_HG * DIMX * 2;           // 8 MB
    u16* woutt = (u16*)(ws + off);     off += (size_t)DIMX * DIM_INNER * 2;      // 4 MB
    u16* hg = (u16*)(ws + off);        off += (size_t)M_TOTAL * N_HG * 2;        // 128 MB
    uint32_t* hbuf = (uint32_t*)(ws + off); off += (size_t)M_TOTAL * DIM_INNER * 2; // 64 MB
    // sumAV (8 MB) + carry (4 MB) alias xb's region: xb is dead after GEMM1,
    // and GEMM1 completes before scan_chunks on the same stream.
    float2* sumAV = (float2*)(ws + 0);
    float* carry = (float*)(ws + (size_t)BATCH * NCHUNK * DIM_INNER * 8);

    // 1. fused prep: cast x, transpose Whg, transpose Wout
    prep<<<2048 + 1024 + 512, 256, 0, stream>>>(x, Whg, Wout, xb, whgt, woutt);

    // 2. GEMM1: hg[16384][4096] = xb @ Whg   (bf16 out)
    gemm_bf16<1><<<dim3(N_HG / 128, M_TOTAL / 128), 256, 0, stream>>>(xb, whgt, hg, M_TOTAL, N_HG, DIMX);

    // 3. chunked scan over S
    scan_chunks<<<dim3(NCHUNK, BATCH), 256, 0, stream>>>(hg, sumAV);
    scan_carry<<<dim3(128), 64, 0, stream>>>(sumAV, carry);
    scan_apply<<<dim3(NCHUNK, BATCH), 256, 0, stream>>>(hg, carry, hbuf);

    // 4. GEMM2: out[16384][1024] = h @ Wout  (fp32 out)
    gemm_bf16<0><<<dim3(DIMX / 128, M_TOTAL / 128), 256, 0, stream>>>((const u16*)hbuf, woutt, d_out, M_TOTAL, DIMX, DIM_INNER);
}